// Round 3
// baseline (1452.919 us; speedup 1.0000x reference)
//
#include <hip/hip_runtime.h>

// PointNet 2-stage fused pipeline, MI355X gfx950.  Round 3.
// - counting-sort by voxel; segment-max fused into GEMM epilogues with
//   interior-run plain stores + edge atomicMax (sorted rows).
// - f16 MFMA (16x16x32) everywhere incl. final layer (f32 accum).
// - N=256 GEMMs: 512-thread blocks (8 waves, full-N), 3 blocks/CU.
// - ws_size-adaptive: materialize pf2 (skip recompute) when workspace allows.

#define NPTS 524288
#define NVOX 32768

typedef _Float16 f16;
typedef _Float16 f16x8 __attribute__((ext_vector_type(8)));
typedef float f32x4 __attribute__((ext_vector_type(4)));

#define GLDS16(g, l)                                                          \
  __builtin_amdgcn_global_load_lds(                                           \
      (const __attribute__((address_space(1))) unsigned int*)(const void*)(g),\
      (__attribute__((address_space(3))) unsigned int*)(void*)(l), 16, 0, 0)

// ---------- idx normalization: auto-detect int32 vs int64 storage ----------
__global__ void k_fixidx(const int* __restrict__ raw, int* __restrict__ out) {
  bool is64 = true;
#pragma unroll
  for (int k = 0; k < 32; ++k)
    if (raw[2 * k + 1] != 0) is64 = false;   // int64 high words all 0 (vals < 32768)
  int stride = gridDim.x * blockDim.x;
  for (int i = blockIdx.x * blockDim.x + threadIdx.x; i < NPTS; i += stride)
    out[i] = is64 ? raw[2 * i] : raw[i];
}

// ---------- counting sort ----------
__global__ void k_hist(const int* __restrict__ idx, int* __restrict__ counts) {
  int stride = gridDim.x * blockDim.x;
  for (int i = blockIdx.x * blockDim.x + threadIdx.x; i < NPTS; i += stride)
    atomicAdd(&counts[idx[i]], 1);
}

__global__ void k_scan(const int* __restrict__ counts, int* __restrict__ offsets) {
  __shared__ int part[1024];
  __shared__ int sums[32];
  int t = threadIdx.x;
  int loc[32];
  int s = 0;
#pragma unroll
  for (int j = 0; j < 32; ++j) { loc[j] = counts[t * 32 + j]; s += loc[j]; }
  part[t] = s;
  __syncthreads();
  if (t < 32) {
    int run = 0;
    for (int j = 0; j < 32; ++j) { int tmp = part[t * 32 + j]; part[t * 32 + j] = run; run += tmp; }
    sums[t] = run;
  }
  __syncthreads();
  if (t == 0) {
    int run = 0;
    for (int i = 0; i < 32; ++i) { int tmp = sums[i]; sums[i] = run; run += tmp; }
  }
  __syncthreads();
  int b = part[t] + sums[t >> 5];
#pragma unroll
  for (int j = 0; j < 32; ++j) { offsets[t * 32 + j] = b; b += loc[j]; }
  if (t == 1023) offsets[NVOX] = b;
}

__global__ void k_scat(const int* __restrict__ idx, const int* __restrict__ offsets,
                       int* __restrict__ cursor, int* __restrict__ sp, int* __restrict__ sv) {
  int stride = gridDim.x * blockDim.x;
  for (int i = blockIdx.x * blockDim.x + threadIdx.x; i < NPTS; i += stride) {
    int v = idx[i];
    int pos = offsets[v] + atomicAdd(&cursor[v], 1);
    sp[pos] = i;
    sv[pos] = v;
  }
}

// ---------- weight transpose+cast: Wt[n][k] = (f16)W[k][n] ----------
__global__ void k_wcast(const float* __restrict__ W, f16* __restrict__ Wt, int K, int N) {
  int g = blockIdx.x * blockDim.x + threadIdx.x;
  if (g >= K * N) return;
  int k = g / N, n = g % N;
  Wt[n * K + k] = (f16)W[g];
}

__global__ void k_castf(const float* __restrict__ in, f16* __restrict__ out, int n) {
  int stride = gridDim.x * blockDim.x;
  for (int i = blockIdx.x * blockDim.x + threadIdx.x; i < n; i += stride)
    out[i] = (f16)in[i];
}

// ---------- f16 MFMA GEMM: C = relu(A' @ B + bias), BM=128, BN=N -----------
// THREADS = 512 for N=256 (8 waves 2x4), 256 for N=128 (4 waves 2x2).
// MODEA 0: A'[r] = A[tm*128+r]            ([rows][K] f16 contiguous)
// MODEA 1: A'[r] = concat(A2[sv[gr]](128), A[tm*128+r](128)), K=256
// MODEA 2: A'[r] = f16(relu(x[sp[gr]] @ W1 + b1))  (mlp1 on the fly, K=64)
// WRITEO: write relu(acc+bias) to Of16 (or Of32 if OUTF32)
// SCATTER: run-reduce sorted-voxel rows; interior runs plain-store, edge
//          runs atomicMax into Of32[v][N]
template <int K, int N, int MODEA, bool SCATTER, bool OUTF32, bool WRITEO>
__global__ __launch_bounds__(N == 256 ? 512 : 256, N == 256 ? 6 : 4) void k_gemm(
    const f16* __restrict__ A, const f16* __restrict__ A2,
    const int* __restrict__ sv, const int* __restrict__ sp,
    const int* __restrict__ offs,
    const float* __restrict__ x, const float* __restrict__ W1, const float* __restrict__ b1,
    const f16* __restrict__ Bt,   // [N][K] pre-transposed
    const float* __restrict__ bias,
    f16* __restrict__ Of16, float* __restrict__ Of32, int row0) {
  constexpr int THREADS = (N == 256) ? 512 : 256;
  constexpr int WN = N / 64;                    // waves along N
  constexpr int SMEMB = 128 * 64 * 2 + N * 64 * 2;   // As + Bs
  __shared__ __align__(16) char smem[SMEMB];
  __shared__ float xs[MODEA == 2 ? 768 : 1];
  __shared__ int svp[MODEA == 2 ? 128 : 1];
  __shared__ int svx[(MODEA == 1 || SCATTER) ? 128 : 1];
  f16* As = (f16*)smem;            // [128][64] per K-tile, 16B chunks XOR-swizzled
  f16* Bs = As + 128 * 64;         // [N][64]

  int nwg = gridDim.x;             // all grids are multiples of 8
  int bid = blockIdx.x;
  int q = nwg >> 3;
  int tm = (bid & 7) * q + (bid >> 3);   // bijective XCD swizzle
  int t = threadIdx.x;

  if (MODEA == 2) { if (t < 128) svp[t] = sp[row0 + tm * 128 + t]; }
  if (MODEA == 1 || SCATTER) { if (t < 128) svx[t] = sv[row0 + tm * 128 + t]; }
  if (MODEA == 1 || MODEA == 2) __syncthreads();

  int l = t & 63, w = t >> 6;
  int wm = w / WN, wn = w % WN;
  int lrow = l & 15, lk = l >> 4;
  f32x4 acc[4][4] = {};

  constexpr int KT = K / 64;
  constexpr int AIT = (128 * 64 / 8) / THREADS;  // A 16B-chunks per thread
  constexpr int BIT = (N * 64 / 8) / THREADS;    // B 16B-chunks per thread
#pragma unroll
  for (int kt = 0; kt < KT; ++kt) {
    int k0 = kt * 64;
    // ---- stage B first (issue async loads early)
#pragma unroll
    for (int i = 0; i < BIT; ++i) {
      int g = i * THREADS + t;
      int n = g >> 3;
      int clog = (g & 7) ^ (n & 7);
      GLDS16(Bt + (size_t)n * K + k0 + clog * 8, Bs + g * 8);
    }
    if constexpr (MODEA == 2) {
      for (int g = t; g < 768; g += THREADS) xs[g] = x[(size_t)svp[g / 6] * 6 + (g % 6)];
      __syncthreads();
      int j = t & 63;
      float wv[6];
#pragma unroll
      for (int i = 0; i < 6; ++i) wv[i] = W1[i * 64 + j];
      float bb = b1[j];
      int rb = (t >> 6) * 32;
#pragma unroll
      for (int rr = 0; rr < 32; ++rr) {
        int row = rb + rr;
        float a = bb;
#pragma unroll
        for (int i = 0; i < 6; ++i) a += xs[row * 6 + i] * wv[i];
        As[row * 64 + (((j >> 3) ^ (row & 7)) << 3) + (j & 7)] = (f16)fmaxf(a, 0.f);
      }
    } else {
#pragma unroll
      for (int i = 0; i < AIT; ++i) {
        int g = i * THREADS + t;
        int row = g >> 3;
        int clog = (g & 7) ^ (row & 7);
        const f16* src;
        if constexpr (MODEA == 0) {
          src = A + (size_t)(tm * 128 + row) * K + k0 + clog * 8;
        } else {  // MODEA == 1: gather-concat
          if (k0 < 128) src = A2 + (size_t)svx[row] * 128 + k0 + clog * 8;
          else          src = A + (size_t)(tm * 128 + row) * 128 + (k0 - 128) + clog * 8;
        }
        GLDS16(src, As + g * 8);
      }
    }
    __syncthreads();   // compiler drains vmcnt+lgkmcnt before barrier
#pragma unroll
    for (int ks = 0; ks < 2; ++ks) {
      f16x8 af[4], bf[4];
#pragma unroll
      for (int m = 0; m < 4; ++m) {
        int row = wm * 64 + m * 16 + lrow;
        int cp = (ks * 4 + lk) ^ (row & 7);
        af[m] = *(const f16x8*)(As + row * 64 + cp * 8);
      }
#pragma unroll
      for (int n = 0; n < 4; ++n) {
        int col = wn * 64 + n * 16 + lrow;
        int cp = (ks * 4 + lk) ^ (col & 7);
        bf[n] = *(const f16x8*)(Bs + col * 64 + cp * 8);
      }
#pragma unroll
      for (int m = 0; m < 4; ++m)
#pragma unroll
        for (int n = 0; n < 4; ++n)
          acc[m][n] = __builtin_amdgcn_mfma_f32_16x16x32_f16(af[m], bf[n], acc[m][n], 0, 0, 0);
    }
    __syncthreads();
  }

  if constexpr (WRITEO) {
#pragma unroll
    for (int m = 0; m < 4; ++m)
#pragma unroll
      for (int n = 0; n < 4; ++n)
#pragma unroll
        for (int j = 0; j < 4; ++j) {
          int row = wm * 64 + m * 16 + lk * 4 + j;   // C/D: row=(l>>4)*4+j
          int gc  = wn * 64 + n * 16 + lrow;         //      col=l&15
          float val = fmaxf(acc[m][n][j] + bias[gc], 0.f);
          if constexpr (OUTF32) Of32[(size_t)(tm * 128 + row) * N + gc] = val;
          else                  Of16[(size_t)(tm * 128 + row) * N + gc] = (f16)val;
        }
  }

  if constexpr (SCATTER && N == 128) {
    f16* tile = (f16*)smem;   // [128][128] f16 (32KB, reuses As/Bs)
#pragma unroll
    for (int m = 0; m < 4; ++m)
#pragma unroll
      for (int n = 0; n < 4; ++n)
#pragma unroll
        for (int j = 0; j < 4; ++j) {
          int row = wm * 64 + m * 16 + lk * 4 + j;
          int col = wn * 64 + n * 16 + lrow;
          tile[row * 128 + col] = (f16)fmaxf(acc[m][n][j] + bias[col], 0.f);
        }
    __syncthreads();
    int c = t & 127, h = t >> 7;
    int r0l = h * 64;
    int gc = c;
    int grow0 = row0 + tm * 128 + r0l;
    float run = 0.f;
    int curv = svx[r0l];
    for (int r = r0l; r < r0l + 64; ++r) {
      int v = svx[r];
      if (v != curv) {
        bool inter = (offs[curv] >= grow0) && (offs[curv + 1] <= grow0 + 64);
        if (inter) Of32[(size_t)curv * N + gc] = run;
        else atomicMax((int*)&Of32[(size_t)curv * N + gc], __float_as_int(run));
        curv = v; run = 0.f;
      }
      run = fmaxf(run, (float)tile[r * 128 + c]);
    }
    bool inter = (offs[curv] >= grow0) && (offs[curv + 1] <= grow0 + 64);
    if (inter) Of32[(size_t)curv * N + gc] = run;
    else atomicMax((int*)&Of32[(size_t)curv * N + gc], __float_as_int(run));
  }

  if constexpr (SCATTER && N == 256) {
    f16* tile = (f16*)smem;   // [128][128] per column-half (32KB)
#pragma unroll
    for (int H = 0; H < 2; ++H) {
      __syncthreads();        // prev reads of smem done
      if ((wn >> 1) == H) {
        int cb = (wn & 1) * 64;
#pragma unroll
        for (int m = 0; m < 4; ++m)
#pragma unroll
          for (int n = 0; n < 4; ++n)
#pragma unroll
            for (int j = 0; j < 4; ++j) {
              int row = wm * 64 + m * 16 + lk * 4 + j;
              int cl_ = cb + n * 16 + lrow;
              tile[row * 128 + cl_] =
                  (f16)fmaxf(acc[m][n][j] + bias[H * 128 + cl_], 0.f);
            }
      }
      __syncthreads();
      int c = t & 127, seg = t >> 7;     // 4 segments x 32 rows
      int r0l = seg * 32;
      int gc = H * 128 + c;
      int grow0 = row0 + tm * 128 + r0l;
      float run = 0.f;
      int curv = svx[r0l];
      for (int r = r0l; r < r0l + 32; ++r) {
        int v = svx[r];
        if (v != curv) {
          bool inter = (offs[curv] >= grow0) && (offs[curv + 1] <= grow0 + 32);
          if (inter) Of32[(size_t)curv * N + gc] = run;
          else atomicMax((int*)&Of32[(size_t)curv * N + gc], __float_as_int(run));
          curv = v; run = 0.f;
        }
        run = fmaxf(run, (float)tile[r * 128 + c]);
      }
      bool inter = (offs[curv] >= grow0) && (offs[curv + 1] <= grow0 + 32);
      if (inter) Of32[(size_t)curv * N + gc] = run;
      else atomicMax((int*)&Of32[(size_t)curv * N + gc], __float_as_int(run));
    }
  }
}

extern "C" void kernel_launch(void* const* d_in, const int* in_sizes, int n_in,
                              void* d_out, int out_size, void* d_ws, size_t ws_size,
                              hipStream_t stream) {
  const float* x   = (const float*)d_in[0];
  const int*  idxr = (const int*)d_in[1];
  const float* W1  = (const float*)d_in[3];
  const float* b1  = (const float*)d_in[4];
  const float* W2  = (const float*)d_in[5];
  const float* b2  = (const float*)d_in[6];
  const float* Wv1 = (const float*)d_in[7];
  const float* bv1 = (const float*)d_in[8];
  const float* W3  = (const float*)d_in[9];
  const float* b3  = (const float*)d_in[10];
  const float* W4  = (const float*)d_in[11];
  const float* b4  = (const float*)d_in[12];
  const float* Wv2 = (const float*)d_in[13];
  const float* bv2 = (const float*)d_in[14];
  float* out = (float*)d_out;

  char* ws = (char*)d_ws;
  size_t off = 0;
  auto alloc = [&](size_t bytes) {
    void* p = ws + off;
    off = (off + bytes + 255) & ~(size_t)255;
    return p;
  };
  int* idx     = (int*)alloc((size_t)NPTS * 4);
  int* counts  = (int*)alloc((size_t)NVOX * 4);
  int* cursor  = (int*)alloc((size_t)NVOX * 4);
  int* offs    = (int*)alloc((size_t)(NVOX + 1) * 4);
  int* sp      = (int*)alloc((size_t)NPTS * 4);
  int* sv      = (int*)alloc((size_t)NPTS * 4);
  f16* W2t     = (f16*)alloc(64 * 128 * 2);
  f16* Wv1t    = (f16*)alloc(128 * 128 * 2);
  f16* W3t     = (f16*)alloc(256 * 256 * 2);
  f16* W4t     = (f16*)alloc(256 * 256 * 2);
  f16* Wv2t    = (f16*)alloc(256 * 256 * 2);
  float* vox1f = (float*)alloc((size_t)NVOX * 128 * 4);
  f16* vox1h   = (f16*)alloc((size_t)NVOX * 128 * 2);
  f16* occ1    = (f16*)alloc((size_t)NVOX * 128 * 2);
  float* vox2f = (float*)alloc((size_t)NVOX * 256 * 4);

  // adaptive tail: [pf2 full]? + pf4c chunk
  size_t rem = (ws_size > off) ? ws_size - off : 0;
  bool PF2FULL;
  int CH;
  if (rem >= (size_t)NPTS * 256 + (size_t)131072 * 512 + 4096) {
    PF2FULL = true;  CH = 131072;
  } else if (rem >= (size_t)NPTS * 256 + (size_t)65536 * 512 + 4096) {
    PF2FULL = true;  CH = 65536;
  } else {
    PF2FULL = false; CH = 65536;
  }
  f16* pf2  = (f16*)alloc(PF2FULL ? (size_t)NPTS * 256 : (size_t)CH * 256);
  f16* pf4c = (f16*)alloc((size_t)CH * 512);
  f16* vox2h = PF2FULL ? pf2 : pf4c;   // overlay: dead by the time vox2h is written

  hipMemsetAsync(counts, 0, (size_t)NVOX * 4, stream);
  hipMemsetAsync(cursor, 0, (size_t)NVOX * 4, stream);
  hipMemsetAsync(vox1f, 0, (size_t)NVOX * 128 * 4, stream);
  hipMemsetAsync(vox2f, 0, (size_t)NVOX * 256 * 4, stream);

  k_fixidx<<<2048, 256, 0, stream>>>(idxr, idx);
  k_wcast<<<(64 * 128 + 255) / 256, 256, 0, stream>>>(W2, W2t, 64, 128);
  k_wcast<<<(128 * 128 + 255) / 256, 256, 0, stream>>>(Wv1, Wv1t, 128, 128);
  k_wcast<<<(256 * 256 + 255) / 256, 256, 0, stream>>>(W3, W3t, 256, 256);
  k_wcast<<<(256 * 256 + 255) / 256, 256, 0, stream>>>(W4, W4t, 256, 256);
  k_wcast<<<(256 * 256 + 255) / 256, 256, 0, stream>>>(Wv2, Wv2t, 256, 256);
  k_hist<<<2048, 256, 0, stream>>>(idx, counts);
  k_scan<<<1, 1024, 0, stream>>>(counts, offs);
  k_scat<<<2048, 256, 0, stream>>>(idx, offs, cursor, sp, sv);

  // P1: fused mlp1+mm2 + segment-max -> vox1f (optionally also writes pf2)
  if (PF2FULL)
    k_gemm<64, 128, 2, true, false, true><<<NPTS / 128, 256, 0, stream>>>(
        nullptr, nullptr, sv, sp, offs, x, W1, b1, W2t, b2, pf2, vox1f, 0);
  else
    k_gemm<64, 128, 2, true, false, false><<<NPTS / 128, 256, 0, stream>>>(
        nullptr, nullptr, sv, sp, offs, x, W1, b1, W2t, b2, nullptr, vox1f, 0);
  k_castf<<<2048, 256, 0, stream>>>(vox1f, vox1h, NVOX * 128);
  // mmv1: occ1 = relu(vox1 @ Wv1 + bv1)
  k_gemm<128, 128, 0, false, false, true><<<NVOX / 128, 256, 0, stream>>>(
      vox1h, nullptr, nullptr, nullptr, nullptr, nullptr, nullptr, nullptr,
      Wv1t, bv1, occ1, nullptr, 0);

  // stage 2, chunked
  int nchunk = NPTS / CH;
  for (int c = 0; c < nchunk; ++c) {
    int row0 = c * CH;
    const f16* pf2c = PF2FULL ? pf2 + (size_t)row0 * 128 : pf2;
    if (!PF2FULL)
      k_gemm<64, 128, 2, false, false, true><<<CH / 128, 256, 0, stream>>>(
          nullptr, nullptr, nullptr, sp, nullptr, x, W1, b1, W2t, b2,
          pf2, nullptr, row0);
    // mm3: pf4c = relu(concat(occ1[sv], pf2) @ W3 + b3)
    k_gemm<256, 256, 1, false, false, true><<<CH / 128, 512, 0, stream>>>(
        pf2c, occ1, sv, nullptr, nullptr, nullptr, nullptr, nullptr,
        W3t, b3, pf4c, nullptr, row0);
    // mm4 + scatter-max into vox2f
    k_gemm<256, 256, 0, true, false, false><<<CH / 128, 512, 0, stream>>>(
        pf4c, nullptr, sv, nullptr, offs, nullptr, nullptr, nullptr,
        W4t, b4, nullptr, vox2f, row0);
  }

  k_castf<<<2048, 256, 0, stream>>>(vox2f, vox2h, NVOX * 256);
  // mmv2: out = relu(vox2 @ Wv2 + bv2), f32 output via MFMA
  k_gemm<256, 256, 0, false, true, true><<<NVOX / 128, 512, 0, stream>>>(
      vox2h, nullptr, nullptr, nullptr, nullptr, nullptr, nullptr, nullptr,
      Wv2t, bv2, nullptr, out, 0);
}

// Round 4
// 592.413 us; speedup vs baseline: 2.4525x; 2.4525x over previous
//
#include <hip/hip_runtime.h>

// PointNet 2-stage fused pipeline, MI355X gfx950.  Round 4.
// Round-2 proven GEMM core (256 threads, 128x128 tile per block, NT split for
// N=256), f16 MFMA 16x16x32, global_load_lds(16B), XOR-swizzled LDS.
// Deltas vs round 2: pf2 materialized by P1 (no recompute), interior-run
// plain-store scatter, final layer via MFMA (f32 out). 512-thread variant
// from round 3 removed (3x per-point regression, pathological occupancy).

#define NPTS 524288
#define NVOX 32768

typedef _Float16 f16;
typedef _Float16 f16x8 __attribute__((ext_vector_type(8)));
typedef float f32x4 __attribute__((ext_vector_type(4)));

#define GLDS16(g, l)                                                          \
  __builtin_amdgcn_global_load_lds(                                           \
      (const __attribute__((address_space(1))) unsigned int*)(const void*)(g),\
      (__attribute__((address_space(3))) unsigned int*)(void*)(l), 16, 0, 0)

// ---------- idx normalization: auto-detect int32 vs int64 storage ----------
__global__ void k_fixidx(const int* __restrict__ raw, int* __restrict__ out) {
  bool is64 = true;
#pragma unroll
  for (int k = 0; k < 32; ++k)
    if (raw[2 * k + 1] != 0) is64 = false;   // int64 high words all 0 (vals < 32768)
  int stride = gridDim.x * blockDim.x;
  for (int i = blockIdx.x * blockDim.x + threadIdx.x; i < NPTS; i += stride)
    out[i] = is64 ? raw[2 * i] : raw[i];
}

// ---------- counting sort ----------
__global__ void k_hist(const int* __restrict__ idx, int* __restrict__ counts) {
  int stride = gridDim.x * blockDim.x;
  for (int i = blockIdx.x * blockDim.x + threadIdx.x; i < NPTS; i += stride)
    atomicAdd(&counts[idx[i]], 1);
}

__global__ void k_scan(const int* __restrict__ counts, int* __restrict__ offsets) {
  __shared__ int part[1024];
  __shared__ int sums[32];
  int t = threadIdx.x;
  int loc[32];
  int s = 0;
#pragma unroll
  for (int j = 0; j < 32; ++j) { loc[j] = counts[t * 32 + j]; s += loc[j]; }
  part[t] = s;
  __syncthreads();
  if (t < 32) {
    int run = 0;
    for (int j = 0; j < 32; ++j) { int tmp = part[t * 32 + j]; part[t * 32 + j] = run; run += tmp; }
    sums[t] = run;
  }
  __syncthreads();
  if (t == 0) {
    int run = 0;
    for (int i = 0; i < 32; ++i) { int tmp = sums[i]; sums[i] = run; run += tmp; }
  }
  __syncthreads();
  int b = part[t] + sums[t >> 5];
#pragma unroll
  for (int j = 0; j < 32; ++j) { offsets[t * 32 + j] = b; b += loc[j]; }
  if (t == 1023) offsets[NVOX] = b;
}

__global__ void k_scat(const int* __restrict__ idx, const int* __restrict__ offsets,
                       int* __restrict__ cursor, int* __restrict__ sp, int* __restrict__ sv) {
  int stride = gridDim.x * blockDim.x;
  for (int i = blockIdx.x * blockDim.x + threadIdx.x; i < NPTS; i += stride) {
    int v = idx[i];
    int pos = offsets[v] + atomicAdd(&cursor[v], 1);
    sp[pos] = i;
    sv[pos] = v;
  }
}

// ---------- weight transpose+cast: Wt[n][k] = (f16)W[k][n] ----------
__global__ void k_wcast(const float* __restrict__ W, f16* __restrict__ Wt, int K, int N) {
  int g = blockIdx.x * blockDim.x + threadIdx.x;
  if (g >= K * N) return;
  int k = g / N, n = g % N;
  Wt[n * K + k] = (f16)W[g];
}

__global__ void k_castf(const float* __restrict__ in, f16* __restrict__ out, int n) {
  int stride = gridDim.x * blockDim.x;
  for (int i = blockIdx.x * blockDim.x + threadIdx.x; i < n; i += stride)
    out[i] = (f16)in[i];
}

// ---------- f16 MFMA GEMM: C = relu(A' @ B + bias), 128x128 tile/block -----
// 256 threads, 4 waves (2x2). N=256 handled by NT=2 column-half blocks.
// MODEA 0: A'[r] = A[tm*128+r]            ([rows][K] f16 contiguous)
// MODEA 1: A'[r] = concat(A2[sv[gr]](128), A[tm*128+r](128)), K=256
// MODEA 2: A'[r] = f16(relu(x[sp[gr]] @ W1 + b1))  (mlp1 on the fly, K=64)
// WRITEO: write relu(acc+bias) to Of16 (or Of32 if OUTF32)
// SCATTER: run-reduce sorted-voxel rows; interior runs plain-store, edge
//          runs atomicMax into Of32[v][N]
template <int K, int N, int MODEA, bool SCATTER, bool OUTF32, bool WRITEO>
__global__ __launch_bounds__(256, 3) void k_gemm(
    const f16* __restrict__ A, const f16* __restrict__ A2,
    const int* __restrict__ sv, const int* __restrict__ sp,
    const int* __restrict__ offs,
    const float* __restrict__ x, const float* __restrict__ W1, const float* __restrict__ b1,
    const f16* __restrict__ Bt,   // [N][K] pre-transposed
    const float* __restrict__ bias,
    f16* __restrict__ Of16, float* __restrict__ Of32, int row0) {
  constexpr int NT = N / 128;
  __shared__ __align__(16) char smem[32768];
  __shared__ float xs[MODEA == 2 ? 768 : 1];
  __shared__ int svp[MODEA == 2 ? 128 : 1];
  __shared__ int svx[(MODEA == 1 || SCATTER) ? 128 : 1];
  f16* As = (f16*)smem;            // [128][64] per K-tile, 16B chunks XOR-swizzled
  f16* Bs = As + 128 * 64;

  int nwg = gridDim.x;             // all grids are multiples of 8
  int bid = blockIdx.x;
  int q = nwg >> 3;
  int swz = (bid & 7) * q + (bid >> 3);   // bijective XCD swizzle
  int tm = swz / NT, tn = swz % NT;
  int t = threadIdx.x;

  if (MODEA == 2) { if (t < 128) svp[t] = sp[row0 + tm * 128 + t]; }
  if (MODEA == 1 || SCATTER) { if (t < 128) svx[t] = sv[row0 + tm * 128 + t]; }
  if (MODEA == 1 || MODEA == 2) __syncthreads();

  int l = t & 63, w = t >> 6;
  int wm = w >> 1, wn = w & 1;
  int lrow = l & 15, lk = l >> 4;
  f32x4 acc[4][4] = {};

  constexpr int KT = K / 64;
#pragma unroll
  for (int kt = 0; kt < KT; ++kt) {
    int k0 = kt * 64;
    // ---- stage B first (issue async loads early)
#pragma unroll
    for (int i = 0; i < 4; ++i) {
      int n = i * 32 + (t >> 3);
      int clog = (t & 7) ^ (n & 7);
      GLDS16(Bt + (size_t)(tn * 128 + n) * K + k0 + clog * 8, Bs + i * 2048 + t * 8);
    }
    if constexpr (MODEA == 2) {
      for (int g = t; g < 768; g += 256) xs[g] = x[(size_t)svp[g / 6] * 6 + (g % 6)];
      __syncthreads();
      int j = t & 63;
      float wv[6];
#pragma unroll
      for (int i = 0; i < 6; ++i) wv[i] = W1[i * 64 + j];
      float bb = b1[j];
      int rb = (t >> 6) * 32;
#pragma unroll
      for (int rr = 0; rr < 32; ++rr) {
        int row = rb + rr;
        float a = bb;
#pragma unroll
        for (int i = 0; i < 6; ++i) a += xs[row * 6 + i] * wv[i];
        As[row * 64 + (((j >> 3) ^ (row & 7)) << 3) + (j & 7)] = (f16)fmaxf(a, 0.f);
      }
    } else {
#pragma unroll
      for (int i = 0; i < 4; ++i) {
        int row = i * 32 + (t >> 3);
        int clog = (t & 7) ^ (row & 7);
        const f16* src;
        if constexpr (MODEA == 0) {
          src = A + (size_t)(tm * 128 + row) * K + k0 + clog * 8;
        } else {  // MODEA == 1: gather-concat
          if (k0 < 128) src = A2 + (size_t)svx[row] * 128 + k0 + clog * 8;
          else          src = A + (size_t)(tm * 128 + row) * 128 + (k0 - 128) + clog * 8;
        }
        GLDS16(src, As + i * 2048 + t * 8);
      }
    }
    __syncthreads();   // compiler drains vmcnt+lgkmcnt before barrier
#pragma unroll
    for (int ks = 0; ks < 2; ++ks) {
      f16x8 af[4], bf[4];
#pragma unroll
      for (int m = 0; m < 4; ++m) {
        int row = wm * 64 + m * 16 + lrow;
        int cp = (ks * 4 + lk) ^ (row & 7);
        af[m] = *(const f16x8*)(As + row * 64 + cp * 8);
      }
#pragma unroll
      for (int n = 0; n < 4; ++n) {
        int col = wn * 64 + n * 16 + lrow;
        int cp = (ks * 4 + lk) ^ (col & 7);
        bf[n] = *(const f16x8*)(Bs + col * 64 + cp * 8);
      }
#pragma unroll
      for (int m = 0; m < 4; ++m)
#pragma unroll
        for (int n = 0; n < 4; ++n)
          acc[m][n] = __builtin_amdgcn_mfma_f32_16x16x32_f16(af[m], bf[n], acc[m][n], 0, 0, 0);
    }
    __syncthreads();
  }

  if constexpr (WRITEO) {
#pragma unroll
    for (int m = 0; m < 4; ++m)
#pragma unroll
      for (int n = 0; n < 4; ++n)
#pragma unroll
        for (int j = 0; j < 4; ++j) {
          int row = wm * 64 + m * 16 + lk * 4 + j;   // C/D: row=(l>>4)*4+j
          int gc  = tn * 128 + wn * 64 + n * 16 + lrow;  // col=l&15
          float val = fmaxf(acc[m][n][j] + bias[gc], 0.f);
          if constexpr (OUTF32) Of32[(size_t)(tm * 128 + row) * N + gc] = val;
          else                  Of16[(size_t)(tm * 128 + row) * N + gc] = (f16)val;
        }
  }

  if constexpr (SCATTER) {
    f16* tile = (f16*)smem;   // [128][128] f16 (32KB, reuses As/Bs)
#pragma unroll
    for (int m = 0; m < 4; ++m)
#pragma unroll
      for (int n = 0; n < 4; ++n)
#pragma unroll
        for (int j = 0; j < 4; ++j) {
          int row = wm * 64 + m * 16 + lk * 4 + j;
          int col = wn * 64 + n * 16 + lrow;
          tile[row * 128 + col] =
              (f16)fmaxf(acc[m][n][j] + bias[tn * 128 + col], 0.f);
        }
    __syncthreads();
    int c = t & 127, h = t >> 7;    // 2 segments x 64 rows
    int r0l = h * 64;
    int gc = tn * 128 + c;
    int grow0 = row0 + tm * 128 + r0l;
    float run = 0.f;
    int curv = svx[r0l];
    for (int r = r0l; r < r0l + 64; ++r) {
      int v = svx[r];
      if (v != curv) {
        bool inter = (offs[curv] >= grow0) && (offs[curv + 1] <= grow0 + 64);
        if (inter) Of32[(size_t)curv * N + gc] = run;
        else atomicMax((int*)&Of32[(size_t)curv * N + gc], __float_as_int(run));
        curv = v; run = 0.f;
      }
      run = fmaxf(run, (float)tile[r * 128 + c]);
    }
    bool inter = (offs[curv] >= grow0) && (offs[curv + 1] <= grow0 + 64);
    if (inter) Of32[(size_t)curv * N + gc] = run;
    else atomicMax((int*)&Of32[(size_t)curv * N + gc], __float_as_int(run));
  }
}

extern "C" void kernel_launch(void* const* d_in, const int* in_sizes, int n_in,
                              void* d_out, int out_size, void* d_ws, size_t ws_size,
                              hipStream_t stream) {
  const float* x   = (const float*)d_in[0];
  const int*  idxr = (const int*)d_in[1];
  const float* W1  = (const float*)d_in[3];
  const float* b1  = (const float*)d_in[4];
  const float* W2  = (const float*)d_in[5];
  const float* b2  = (const float*)d_in[6];
  const float* Wv1 = (const float*)d_in[7];
  const float* bv1 = (const float*)d_in[8];
  const float* W3  = (const float*)d_in[9];
  const float* b3  = (const float*)d_in[10];
  const float* W4  = (const float*)d_in[11];
  const float* b4  = (const float*)d_in[12];
  const float* Wv2 = (const float*)d_in[13];
  const float* bv2 = (const float*)d_in[14];
  float* out = (float*)d_out;

  char* ws = (char*)d_ws;
  size_t off = 0;
  auto alloc = [&](size_t bytes) {
    void* p = ws + off;
    off = (off + bytes + 255) & ~(size_t)255;
    return p;
  };
  int* idx     = (int*)alloc((size_t)NPTS * 4);
  int* counts  = (int*)alloc((size_t)NVOX * 4);
  int* cursor  = (int*)alloc((size_t)NVOX * 4);
  int* offs    = (int*)alloc((size_t)(NVOX + 1) * 4);
  int* sp      = (int*)alloc((size_t)NPTS * 4);
  int* sv      = (int*)alloc((size_t)NPTS * 4);
  f16* W2t     = (f16*)alloc(64 * 128 * 2);
  f16* Wv1t    = (f16*)alloc(128 * 128 * 2);
  f16* W3t     = (f16*)alloc(256 * 256 * 2);
  f16* W4t     = (f16*)alloc(256 * 256 * 2);
  f16* Wv2t    = (f16*)alloc(256 * 256 * 2);
  float* vox1f = (float*)alloc((size_t)NVOX * 128 * 4);
  f16* vox1h   = (f16*)alloc((size_t)NVOX * 128 * 2);
  f16* occ1    = (f16*)alloc((size_t)NVOX * 128 * 2);
  float* vox2f = (float*)alloc((size_t)NVOX * 256 * 4);

  // adaptive tail: [pf2 full]? + pf4c chunk
  size_t rem = (ws_size > off) ? ws_size - off : 0;
  bool PF2FULL;
  int CH;
  if (rem >= (size_t)NPTS * 256 + (size_t)131072 * 512 + 4096) {
    PF2FULL = true;  CH = 131072;
  } else if (rem >= (size_t)NPTS * 256 + (size_t)65536 * 512 + 4096) {
    PF2FULL = true;  CH = 65536;
  } else {
    PF2FULL = false; CH = 65536;
  }
  f16* pf2  = (f16*)alloc(PF2FULL ? (size_t)NPTS * 256 : (size_t)CH * 256);
  f16* pf4c = (f16*)alloc((size_t)CH * 512);
  f16* vox2h = PF2FULL ? pf2 : pf4c;   // overlay: dead by the time vox2h is written

  hipMemsetAsync(counts, 0, (size_t)NVOX * 4, stream);
  hipMemsetAsync(cursor, 0, (size_t)NVOX * 4, stream);
  hipMemsetAsync(vox1f, 0, (size_t)NVOX * 128 * 4, stream);
  hipMemsetAsync(vox2f, 0, (size_t)NVOX * 256 * 4, stream);

  k_fixidx<<<2048, 256, 0, stream>>>(idxr, idx);
  k_wcast<<<(64 * 128 + 255) / 256, 256, 0, stream>>>(W2, W2t, 64, 128);
  k_wcast<<<(128 * 128 + 255) / 256, 256, 0, stream>>>(Wv1, Wv1t, 128, 128);
  k_wcast<<<(256 * 256 + 255) / 256, 256, 0, stream>>>(W3, W3t, 256, 256);
  k_wcast<<<(256 * 256 + 255) / 256, 256, 0, stream>>>(W4, W4t, 256, 256);
  k_wcast<<<(256 * 256 + 255) / 256, 256, 0, stream>>>(Wv2, Wv2t, 256, 256);
  k_hist<<<2048, 256, 0, stream>>>(idx, counts);
  k_scan<<<1, 1024, 0, stream>>>(counts, offs);
  k_scat<<<2048, 256, 0, stream>>>(idx, offs, cursor, sp, sv);

  // P1: fused mlp1+mm2 + segment-max -> vox1f (optionally also writes pf2)
  if (PF2FULL)
    k_gemm<64, 128, 2, true, false, true><<<NPTS / 128, 256, 0, stream>>>(
        nullptr, nullptr, sv, sp, offs, x, W1, b1, W2t, b2, pf2, vox1f, 0);
  else
    k_gemm<64, 128, 2, true, false, false><<<NPTS / 128, 256, 0, stream>>>(
        nullptr, nullptr, sv, sp, offs, x, W1, b1, W2t, b2, nullptr, vox1f, 0);
  k_castf<<<2048, 256, 0, stream>>>(vox1f, vox1h, NVOX * 128);
  // mmv1: occ1 = relu(vox1 @ Wv1 + bv1)
  k_gemm<128, 128, 0, false, false, true><<<NVOX / 128, 256, 0, stream>>>(
      vox1h, nullptr, nullptr, nullptr, nullptr, nullptr, nullptr, nullptr,
      Wv1t, bv1, occ1, nullptr, 0);

  // stage 2, chunked
  int nchunk = NPTS / CH;
  for (int c = 0; c < nchunk; ++c) {
    int row0 = c * CH;
    const f16* pf2c = PF2FULL ? pf2 + (size_t)row0 * 128 : pf2;
    if (!PF2FULL)
      k_gemm<64, 128, 2, false, false, true><<<CH / 128, 256, 0, stream>>>(
          nullptr, nullptr, nullptr, sp, nullptr, x, W1, b1, W2t, b2,
          pf2, nullptr, row0);
    // mm3: pf4c = relu(concat(occ1[sv], pf2) @ W3 + b3)
    k_gemm<256, 256, 1, false, false, true><<<(CH / 128) * 2, 256, 0, stream>>>(
        pf2c, occ1, sv, nullptr, nullptr, nullptr, nullptr, nullptr,
        W3t, b3, pf4c, nullptr, row0);
    // mm4 + scatter-max into vox2f
    k_gemm<256, 256, 0, true, false, false><<<(CH / 128) * 2, 256, 0, stream>>>(
        pf4c, nullptr, sv, nullptr, offs, nullptr, nullptr, nullptr,
        W4t, b4, nullptr, vox2f, row0);
  }

  k_castf<<<2048, 256, 0, stream>>>(vox2f, vox2h, NVOX * 256);
  // mmv2: out = relu(vox2 @ Wv2 + bv2), f32 output via MFMA
  k_gemm<256, 256, 0, false, true, true><<<(NVOX / 128) * 2, 256, 0, stream>>>(
      vox2h, nullptr, nullptr, nullptr, nullptr, nullptr, nullptr, nullptr,
      Wv2t, bv2, nullptr, out, 0);
}

// Round 5
// 506.183 us; speedup vs baseline: 2.8703x; 1.1704x over previous
//
#include <hip/hip_runtime.h>

// PointNet 2-stage fused pipeline, MI355X gfx950.  Round 5.
// New: k_stage2 fuses mm3+mm4+scatter-max into one kernel; pf4 lives in LDS
// (XOR-swizzled), never touches HBM (saves 512MB round-trip + mm4 A-staging).
// 64-row blocks, 256 thr, 2 blocks/CU (LDS 57.6KB), launch_bounds(256,2)
// [round-3 lesson: min-waves arg caps VGPRs -> (512,6) caused spill storm].
// P1 (fused mlp1+mm2+segmax), mmv1, mmv2 unchanged from validated round 4.

#define NPTS 524288
#define NVOX 32768

typedef _Float16 f16;
typedef _Float16 f16x8 __attribute__((ext_vector_type(8)));
typedef float f32x4 __attribute__((ext_vector_type(4)));

#define GLDS16(g, l)                                                          \
  __builtin_amdgcn_global_load_lds(                                           \
      (const __attribute__((address_space(1))) unsigned int*)(const void*)(g),\
      (__attribute__((address_space(3))) unsigned int*)(void*)(l), 16, 0, 0)

// ---------- idx normalization: auto-detect int32 vs int64 storage ----------
__global__ void k_fixidx(const int* __restrict__ raw, int* __restrict__ out) {
  bool is64 = true;
#pragma unroll
  for (int k = 0; k < 32; ++k)
    if (raw[2 * k + 1] != 0) is64 = false;   // int64 high words all 0 (vals < 32768)
  int stride = gridDim.x * blockDim.x;
  for (int i = blockIdx.x * blockDim.x + threadIdx.x; i < NPTS; i += stride)
    out[i] = is64 ? raw[2 * i] : raw[i];
}

// ---------- counting sort ----------
__global__ void k_hist(const int* __restrict__ idx, int* __restrict__ counts) {
  int stride = gridDim.x * blockDim.x;
  for (int i = blockIdx.x * blockDim.x + threadIdx.x; i < NPTS; i += stride)
    atomicAdd(&counts[idx[i]], 1);
}

__global__ void k_scan(const int* __restrict__ counts, int* __restrict__ offsets) {
  __shared__ int part[1024];
  __shared__ int sums[32];
  int t = threadIdx.x;
  int loc[32];
  int s = 0;
#pragma unroll
  for (int j = 0; j < 32; ++j) { loc[j] = counts[t * 32 + j]; s += loc[j]; }
  part[t] = s;
  __syncthreads();
  if (t < 32) {
    int run = 0;
    for (int j = 0; j < 32; ++j) { int tmp = part[t * 32 + j]; part[t * 32 + j] = run; run += tmp; }
    sums[t] = run;
  }
  __syncthreads();
  if (t == 0) {
    int run = 0;
    for (int i = 0; i < 32; ++i) { int tmp = sums[i]; sums[i] = run; run += tmp; }
  }
  __syncthreads();
  int b = part[t] + sums[t >> 5];
#pragma unroll
  for (int j = 0; j < 32; ++j) { offsets[t * 32 + j] = b; b += loc[j]; }
  if (t == 1023) offsets[NVOX] = b;
}

__global__ void k_scat(const int* __restrict__ idx, const int* __restrict__ offsets,
                       int* __restrict__ cursor, int* __restrict__ sp, int* __restrict__ sv) {
  int stride = gridDim.x * blockDim.x;
  for (int i = blockIdx.x * blockDim.x + threadIdx.x; i < NPTS; i += stride) {
    int v = idx[i];
    int pos = offsets[v] + atomicAdd(&cursor[v], 1);
    sp[pos] = i;
    sv[pos] = v;
  }
}

// ---------- weight transpose+cast: Wt[n][k] = (f16)W[k][n] ----------
__global__ void k_wcast(const float* __restrict__ W, f16* __restrict__ Wt, int K, int N) {
  int g = blockIdx.x * blockDim.x + threadIdx.x;
  if (g >= K * N) return;
  int k = g / N, n = g % N;
  Wt[n * K + k] = (f16)W[g];
}

__global__ void k_castf(const float* __restrict__ in, f16* __restrict__ out, int n) {
  int stride = gridDim.x * blockDim.x;
  for (int i = blockIdx.x * blockDim.x + threadIdx.x; i < n; i += stride)
    out[i] = (f16)in[i];
}

// ---------- generic f16 MFMA GEMM (validated round-4 core) -----------------
// 256 thr, 4 waves 2x2, 128x128 tile; N=256 via NT column-half blocks.
// MODEA 0: A'[r]=A[tm*128+r]; MODEA 2: mlp1 on the fly (K=64).
// SCATTER: run-reduced sorted scatter-max; WRITEO: dense output.
template <int K, int N, int MODEA, bool SCATTER, bool OUTF32, bool WRITEO>
__global__ __launch_bounds__(256, 3) void k_gemm(
    const f16* __restrict__ A,
    const int* __restrict__ sv, const int* __restrict__ sp,
    const int* __restrict__ offs,
    const float* __restrict__ x, const float* __restrict__ W1, const float* __restrict__ b1,
    const f16* __restrict__ Bt,   // [N][K] pre-transposed
    const float* __restrict__ bias,
    f16* __restrict__ Of16, float* __restrict__ Of32, int row0) {
  constexpr int NT = N / 128;
  __shared__ __align__(16) char smem[32768];
  __shared__ float xs[MODEA == 2 ? 768 : 1];
  __shared__ int svp[MODEA == 2 ? 128 : 1];
  __shared__ int svx[SCATTER ? 128 : 1];
  f16* As = (f16*)smem;            // [128][64] per K-tile, 16B chunks XOR-swizzled
  f16* Bs = As + 128 * 64;

  int nwg = gridDim.x;             // all grids are multiples of 8
  int bid = blockIdx.x;
  int q = nwg >> 3;
  int swz = (bid & 7) * q + (bid >> 3);   // bijective XCD swizzle
  int tm = swz / NT, tn = swz % NT;
  int t = threadIdx.x;

  if (MODEA == 2) { if (t < 128) svp[t] = sp[row0 + tm * 128 + t]; }
  if (SCATTER) { if (t < 128) svx[t] = sv[row0 + tm * 128 + t]; }
  if (MODEA == 2) __syncthreads();

  int l = t & 63, w = t >> 6;
  int wm = w >> 1, wn = w & 1;
  int lrow = l & 15, lk = l >> 4;
  f32x4 acc[4][4] = {};

  constexpr int KT = K / 64;
#pragma unroll
  for (int kt = 0; kt < KT; ++kt) {
    int k0 = kt * 64;
#pragma unroll
    for (int i = 0; i < 4; ++i) {
      int n = i * 32 + (t >> 3);
      int clog = (t & 7) ^ (n & 7);
      GLDS16(Bt + (size_t)(tn * 128 + n) * K + k0 + clog * 8, Bs + i * 2048 + t * 8);
    }
    if constexpr (MODEA == 2) {
      for (int g = t; g < 768; g += 256) xs[g] = x[(size_t)svp[g / 6] * 6 + (g % 6)];
      __syncthreads();
      int j = t & 63;
      float wv[6];
#pragma unroll
      for (int i = 0; i < 6; ++i) wv[i] = W1[i * 64 + j];
      float bb = b1[j];
      int rb = (t >> 6) * 32;
#pragma unroll
      for (int rr = 0; rr < 32; ++rr) {
        int row = rb + rr;
        float a = bb;
#pragma unroll
        for (int i = 0; i < 6; ++i) a += xs[row * 6 + i] * wv[i];
        As[row * 64 + (((j >> 3) ^ (row & 7)) << 3) + (j & 7)] = (f16)fmaxf(a, 0.f);
      }
    } else {
#pragma unroll
      for (int i = 0; i < 4; ++i) {
        int row = i * 32 + (t >> 3);
        int clog = (t & 7) ^ (row & 7);
        GLDS16(A + (size_t)(tm * 128 + row) * K + k0 + clog * 8, As + i * 2048 + t * 8);
      }
    }
    __syncthreads();
#pragma unroll
    for (int ks = 0; ks < 2; ++ks) {
      f16x8 af[4], bf[4];
#pragma unroll
      for (int m = 0; m < 4; ++m) {
        int row = wm * 64 + m * 16 + lrow;
        int cp = (ks * 4 + lk) ^ (row & 7);
        af[m] = *(const f16x8*)(As + row * 64 + cp * 8);
      }
#pragma unroll
      for (int n = 0; n < 4; ++n) {
        int col = wn * 64 + n * 16 + lrow;
        int cp = (ks * 4 + lk) ^ (col & 7);
        bf[n] = *(const f16x8*)(Bs + col * 64 + cp * 8);
      }
#pragma unroll
      for (int m = 0; m < 4; ++m)
#pragma unroll
        for (int n = 0; n < 4; ++n)
          acc[m][n] = __builtin_amdgcn_mfma_f32_16x16x32_f16(af[m], bf[n], acc[m][n], 0, 0, 0);
    }
    __syncthreads();
  }

  if constexpr (WRITEO) {
#pragma unroll
    for (int m = 0; m < 4; ++m)
#pragma unroll
      for (int n = 0; n < 4; ++n)
#pragma unroll
        for (int j = 0; j < 4; ++j) {
          int row = wm * 64 + m * 16 + lk * 4 + j;       // C/D: row=(l>>4)*4+j
          int gc  = tn * 128 + wn * 64 + n * 16 + lrow;  // col=l&15
          float val = fmaxf(acc[m][n][j] + bias[gc], 0.f);
          if constexpr (OUTF32) Of32[(size_t)(tm * 128 + row) * N + gc] = val;
          else                  Of16[(size_t)(tm * 128 + row) * N + gc] = (f16)val;
        }
  }

  if constexpr (SCATTER) {
    f16* tile = (f16*)smem;   // [128][128] f16 (32KB, reuses As/Bs)
#pragma unroll
    for (int m = 0; m < 4; ++m)
#pragma unroll
      for (int n = 0; n < 4; ++n)
#pragma unroll
        for (int j = 0; j < 4; ++j) {
          int row = wm * 64 + m * 16 + lk * 4 + j;
          int col = wn * 64 + n * 16 + lrow;
          tile[row * 128 + col] =
              (f16)fmaxf(acc[m][n][j] + bias[tn * 128 + col], 0.f);
        }
    __syncthreads();
    int c = t & 127, h = t >> 7;    // 2 segments x 64 rows
    int r0l = h * 64;
    int gc = tn * 128 + c;
    int grow0 = row0 + tm * 128 + r0l;
    float run = 0.f;
    int curv = svx[r0l];
    for (int r = r0l; r < r0l + 64; ++r) {
      int v = svx[r];
      if (v != curv) {
        bool inter = (offs[curv] >= grow0) && (offs[curv + 1] <= grow0 + 64);
        if (inter) Of32[(size_t)curv * N + gc] = run;
        else atomicMax((int*)&Of32[(size_t)curv * N + gc], __float_as_int(run));
        curv = v; run = 0.f;
      }
      run = fmaxf(run, (float)tile[r * 128 + c]);
    }
    bool inter = (offs[curv] >= grow0) && (offs[curv + 1] <= grow0 + 64);
    if (inter) Of32[(size_t)curv * N + gc] = run;
    else atomicMax((int*)&Of32[(size_t)curv * N + gc], __float_as_int(run));
  }
}

// ---------- fused stage 2: mm3 + mm4 + scatter-max, pf4 in LDS -------------
// 64 rows/block, 256 thr (4 waves, 1x4 over 128-col halves).
// pf2 pointer is chunk-local ([local row][128]); sv/offs use row0+global.
__global__ __launch_bounds__(256, 2) void k_stage2(
    const f16* __restrict__ pf2, const f16* __restrict__ occ1,
    const int* __restrict__ sv, const int* __restrict__ offs,
    const f16* __restrict__ W3t, const float* __restrict__ b3,
    const f16* __restrict__ W4t, const float* __restrict__ b4,
    float* __restrict__ vox2f, int row0) {
  __shared__ __align__(16) char smem[24576];     // As 8KB + Bs 16KB
  __shared__ __align__(16) f16 pf4[64 * 256];    // 32KB, chunk-XOR-swizzled
  __shared__ int svx[64];
  f16* As = (f16*)smem;          // [64][64]
  f16* Bs = As + 64 * 64;        // [128][64]
  f16* pf5 = Bs;                 // [64][128] f16, reuses Bs between phases

  int nwg = gridDim.x;
  int bid = blockIdx.x;
  int q = nwg >> 3;
  int bm = (bid & 7) * q + (bid >> 3);   // bijective XCD swizzle
  int t = threadIdx.x;
  if (t < 64) svx[t] = sv[row0 + bm * 64 + t];
  __syncthreads();

  int l = t & 63, w = t >> 6;
  int lrow = l & 15, lk = l >> 4;

  // ---------------- mm3: pf4 = relu(concat(occ1[sv], pf2) @ W3 + b3) -------
#pragma unroll
  for (int h = 0; h < 2; ++h) {
    f32x4 acc[4][2] = {};
#pragma unroll
    for (int kt = 0; kt < 4; ++kt) {
      int k0 = kt * 64;
#pragma unroll
      for (int i = 0; i < 4; ++i) {       // stage B: W3t[h*128+n][k0..]
        int g = i * 256 + t;
        int n = g >> 3;
        int clog = (g & 7) ^ (n & 7);
        GLDS16(W3t + (size_t)(h * 128 + n) * 256 + k0 + clog * 8, Bs + g * 8);
      }
#pragma unroll
      for (int i = 0; i < 2; ++i) {       // stage A: gather-concat
        int g = i * 256 + t;
        int r = g >> 3;
        int clog = (g & 7) ^ (r & 7);
        const f16* src;
        if (k0 < 128) src = occ1 + (size_t)svx[r] * 128 + k0 + clog * 8;
        else          src = pf2 + (size_t)(bm * 64 + r) * 128 + (k0 - 128) + clog * 8;
        GLDS16(src, As + g * 8);
      }
      __syncthreads();
#pragma unroll
      for (int ks = 0; ks < 2; ++ks) {
        f16x8 af[4], bf[2];
#pragma unroll
        for (int m = 0; m < 4; ++m) {
          int row = m * 16 + lrow;
          int cp = (ks * 4 + lk) ^ (row & 7);
          af[m] = *(const f16x8*)(As + row * 64 + cp * 8);
        }
#pragma unroll
        for (int n = 0; n < 2; ++n) {
          int col = w * 32 + n * 16 + lrow;
          int cp = (ks * 4 + lk) ^ (col & 7);
          bf[n] = *(const f16x8*)(Bs + col * 64 + cp * 8);
        }
#pragma unroll
        for (int m = 0; m < 4; ++m)
#pragma unroll
          for (int n = 0; n < 2; ++n)
            acc[m][n] = __builtin_amdgcn_mfma_f32_16x16x32_f16(af[m], bf[n], acc[m][n], 0, 0, 0);
      }
      __syncthreads();
    }
    // write pf4 half into LDS, relu+bias, chunk-XOR swizzle (8-f16 chunks)
#pragma unroll
    for (int m = 0; m < 4; ++m)
#pragma unroll
      for (int n = 0; n < 2; ++n)
#pragma unroll
        for (int j = 0; j < 4; ++j) {
          int row  = m * 16 + lk * 4 + j;
          int colg = h * 128 + w * 32 + n * 16 + lrow;
          int scol = (((colg >> 3) ^ (row & 7)) << 3) | (colg & 7);
          pf4[row * 256 + scol] = (f16)fmaxf(acc[m][n][j] + b3[colg], 0.f);
        }
  }
  __syncthreads();   // pf4 complete

  // ---------------- mm4 + scatter: vox2f = segmax(relu(pf4 @ W4 + b4)) -----
#pragma unroll
  for (int h2 = 0; h2 < 2; ++h2) {
    f32x4 acc[4][2] = {};
#pragma unroll
    for (int kt = 0; kt < 4; ++kt) {
      int k0 = kt * 64;
#pragma unroll
      for (int i = 0; i < 4; ++i) {       // stage B: W4t[h2*128+n][k0..]
        int g = i * 256 + t;
        int n = g >> 3;
        int clog = (g & 7) ^ (n & 7);
        GLDS16(W4t + (size_t)(h2 * 128 + n) * 256 + k0 + clog * 8, Bs + g * 8);
      }
      __syncthreads();
#pragma unroll
      for (int ks = 0; ks < 2; ++ks) {
        f16x8 af[4], bf[2];
#pragma unroll
        for (int m = 0; m < 4; ++m) {     // A from LDS pf4 (swizzled)
          int row = m * 16 + lrow;
          int chunk = kt * 8 + ks * 4 + lk;      // 0..31
          int sc = chunk ^ (row & 7);
          af[m] = *(const f16x8*)(pf4 + row * 256 + sc * 8);
        }
#pragma unroll
        for (int n = 0; n < 2; ++n) {
          int col = w * 32 + n * 16 + lrow;
          int cp = (ks * 4 + lk) ^ (col & 7);
          bf[n] = *(const f16x8*)(Bs + col * 64 + cp * 8);
        }
#pragma unroll
        for (int m = 0; m < 4; ++m)
#pragma unroll
          for (int n = 0; n < 2; ++n)
            acc[m][n] = __builtin_amdgcn_mfma_f32_16x16x32_f16(af[m], bf[n], acc[m][n], 0, 0, 0);
      }
      __syncthreads();
    }
    // pf5 half -> Bs region (Bs dead after last barrier)
#pragma unroll
    for (int m = 0; m < 4; ++m)
#pragma unroll
      for (int n = 0; n < 2; ++n)
#pragma unroll
        for (int j = 0; j < 4; ++j) {
          int row = m * 16 + lk * 4 + j;
          int col = w * 32 + n * 16 + lrow;      // 0..127 within half
          pf5[row * 128 + col] = (f16)fmaxf(acc[m][n][j] + b4[h2 * 128 + col], 0.f);
        }
    __syncthreads();
    // scan: 128 cols x 2 row-segments of 32; interior plain store, edge atomic
    {
      int c = t & 127, seg = t >> 7;
      int r0l = seg * 32;
      int gc = h2 * 128 + c;
      int grow0 = row0 + bm * 64 + r0l;
      float run = 0.f;
      int curv = svx[r0l];
      for (int r = r0l; r < r0l + 32; ++r) {
        int v = svx[r];
        if (v != curv) {
          bool inter = (offs[curv] >= grow0) && (offs[curv + 1] <= grow0 + 32);
          if (inter) vox2f[(size_t)curv * 256 + gc] = run;
          else atomicMax((int*)&vox2f[(size_t)curv * 256 + gc], __float_as_int(run));
          curv = v; run = 0.f;
        }
        run = fmaxf(run, (float)pf5[r * 128 + c]);
      }
      bool inter = (offs[curv] >= grow0) && (offs[curv + 1] <= grow0 + 32);
      if (inter) vox2f[(size_t)curv * 256 + gc] = run;
      else atomicMax((int*)&vox2f[(size_t)curv * 256 + gc], __float_as_int(run));
    }
    __syncthreads();
  }
}

extern "C" void kernel_launch(void* const* d_in, const int* in_sizes, int n_in,
                              void* d_out, int out_size, void* d_ws, size_t ws_size,
                              hipStream_t stream) {
  const float* x   = (const float*)d_in[0];
  const int*  idxr = (const int*)d_in[1];
  const float* W1  = (const float*)d_in[3];
  const float* b1  = (const float*)d_in[4];
  const float* W2  = (const float*)d_in[5];
  const float* b2  = (const float*)d_in[6];
  const float* Wv1 = (const float*)d_in[7];
  const float* bv1 = (const float*)d_in[8];
  const float* W3  = (const float*)d_in[9];
  const float* b3  = (const float*)d_in[10];
  const float* W4  = (const float*)d_in[11];
  const float* b4  = (const float*)d_in[12];
  const float* Wv2 = (const float*)d_in[13];
  const float* bv2 = (const float*)d_in[14];
  float* out = (float*)d_out;

  char* ws = (char*)d_ws;
  size_t off = 0;
  auto alloc = [&](size_t bytes) {
    void* p = ws + off;
    off = (off + bytes + 255) & ~(size_t)255;
    return p;
  };
  int* idx     = (int*)alloc((size_t)NPTS * 4);
  int* counts  = (int*)alloc((size_t)NVOX * 4);
  int* cursor  = (int*)alloc((size_t)NVOX * 4);
  int* offs    = (int*)alloc((size_t)(NVOX + 1) * 4);
  int* sp      = (int*)alloc((size_t)NPTS * 4);
  int* sv      = (int*)alloc((size_t)NPTS * 4);
  f16* W2t     = (f16*)alloc(64 * 128 * 2);
  f16* Wv1t    = (f16*)alloc(128 * 128 * 2);
  f16* W3t     = (f16*)alloc(256 * 256 * 2);
  f16* W4t     = (f16*)alloc(256 * 256 * 2);
  f16* Wv2t    = (f16*)alloc(256 * 256 * 2);
  float* vox1f = (float*)alloc((size_t)NVOX * 128 * 4);
  f16* vox1h   = (f16*)alloc((size_t)NVOX * 128 * 2);
  f16* occ1    = (f16*)alloc((size_t)NVOX * 128 * 2);
  float* vox2f = (float*)alloc((size_t)NVOX * 256 * 4);

  // adaptive: materialize pf2 fully if workspace allows, else chunked recompute
  size_t rem = (ws_size > off) ? ws_size - off : 0;
  bool PF2FULL = rem >= (size_t)NPTS * 256 + 4096;
  int CH = 65536;
  f16* pf2   = (f16*)alloc(PF2FULL ? (size_t)NPTS * 256 : (size_t)CH * 256);
  f16* vox2h = pf2;   // overlay: pf2/pf2c dead once stage2 done (16MB fits both)

  hipMemsetAsync(counts, 0, (size_t)NVOX * 4, stream);
  hipMemsetAsync(cursor, 0, (size_t)NVOX * 4, stream);
  hipMemsetAsync(vox1f, 0, (size_t)NVOX * 128 * 4, stream);
  hipMemsetAsync(vox2f, 0, (size_t)NVOX * 256 * 4, stream);

  k_fixidx<<<2048, 256, 0, stream>>>(idxr, idx);
  k_wcast<<<(64 * 128 + 255) / 256, 256, 0, stream>>>(W2, W2t, 64, 128);
  k_wcast<<<(128 * 128 + 255) / 256, 256, 0, stream>>>(Wv1, Wv1t, 128, 128);
  k_wcast<<<(256 * 256 + 255) / 256, 256, 0, stream>>>(W3, W3t, 256, 256);
  k_wcast<<<(256 * 256 + 255) / 256, 256, 0, stream>>>(W4, W4t, 256, 256);
  k_wcast<<<(256 * 256 + 255) / 256, 256, 0, stream>>>(Wv2, Wv2t, 256, 256);
  k_hist<<<2048, 256, 0, stream>>>(idx, counts);
  k_scan<<<1, 1024, 0, stream>>>(counts, offs);
  k_scat<<<2048, 256, 0, stream>>>(idx, offs, cursor, sp, sv);

  // P1: fused mlp1+mm2 + segment-max -> vox1f (also writes pf2 when it fits)
  if (PF2FULL)
    k_gemm<64, 128, 2, true, false, true><<<NPTS / 128, 256, 0, stream>>>(
        nullptr, sv, sp, offs, x, W1, b1, W2t, b2, pf2, vox1f, 0);
  else
    k_gemm<64, 128, 2, true, false, false><<<NPTS / 128, 256, 0, stream>>>(
        nullptr, sv, sp, offs, x, W1, b1, W2t, b2, nullptr, vox1f, 0);
  k_castf<<<2048, 256, 0, stream>>>(vox1f, vox1h, NVOX * 128);
  // mmv1: occ1 = relu(vox1 @ Wv1 + bv1)
  k_gemm<128, 128, 0, false, false, true><<<NVOX / 128, 256, 0, stream>>>(
      vox1h, nullptr, nullptr, nullptr, nullptr, nullptr, nullptr,
      Wv1t, bv1, occ1, nullptr, 0);

  // stage 2: fused mm3+mm4+scatter (pf4 in LDS)
  if (PF2FULL) {
    k_stage2<<<NPTS / 64, 256, 0, stream>>>(
        pf2, occ1, sv, offs, W3t, b3, W4t, b4, vox2f, 0);
  } else {
    for (int c = 0; c < NPTS / CH; ++c) {
      int row0 = c * CH;
      k_gemm<64, 128, 2, false, false, true><<<CH / 128, 256, 0, stream>>>(
          nullptr, nullptr, sp, nullptr, x, W1, b1, W2t, b2, pf2, nullptr, row0);
      k_stage2<<<CH / 64, 256, 0, stream>>>(
          pf2, occ1, sv, offs, W3t, b3, W4t, b4, vox2f, row0);
    }
  }

  k_castf<<<2048, 256, 0, stream>>>(vox2f, vox2h, NVOX * 256);
  // mmv2: out = relu(vox2 @ Wv2 + bv2), f32 output via MFMA
  k_gemm<256, 256, 0, false, true, true><<<(NVOX / 128) * 2, 256, 0, stream>>>(
      vox2h, nullptr, nullptr, nullptr, nullptr, nullptr, nullptr,
      Wv2t, bv2, nullptr, out, 0);
}

// Round 6
// 416.758 us; speedup vs baseline: 3.4862x; 1.2146x over previous
//
#include <hip/hip_runtime.h>

// PointNet 2-stage fused pipeline, MI355X gfx950.  Round 6.
// k_stage2 v2: 512 thr / 8 waves (both 128-col halves concurrently), 64-row
// blocks, pf4/pf5 padded [64][264] (row stride 528B: near-optimal LDS banking
// for both b128 reads and f16 writes, no XOR needed on pf4).
// launch_bounds(512,2): VGPR cap 256 (round-3 trap was (512,6) -> cap 85 ->
// spill storm; this cannot recur at min-waves=2).
// P1 (fused mlp1+mm2+segmax), mmv1, mmv2, sort: unchanged validated code.

#define NPTS 524288
#define NVOX 32768

typedef _Float16 f16;
typedef _Float16 f16x8 __attribute__((ext_vector_type(8)));
typedef float f32x4 __attribute__((ext_vector_type(4)));

#define GLDS16(g, l)                                                          \
  __builtin_amdgcn_global_load_lds(                                           \
      (const __attribute__((address_space(1))) unsigned int*)(const void*)(g),\
      (__attribute__((address_space(3))) unsigned int*)(void*)(l), 16, 0, 0)

// ---------- idx normalization: auto-detect int32 vs int64 storage ----------
__global__ void k_fixidx(const int* __restrict__ raw, int* __restrict__ out) {
  bool is64 = true;
#pragma unroll
  for (int k = 0; k < 32; ++k)
    if (raw[2 * k + 1] != 0) is64 = false;   // int64 high words all 0 (vals < 32768)
  int stride = gridDim.x * blockDim.x;
  for (int i = blockIdx.x * blockDim.x + threadIdx.x; i < NPTS; i += stride)
    out[i] = is64 ? raw[2 * i] : raw[i];
}

// ---------- counting sort ----------
__global__ void k_hist(const int* __restrict__ idx, int* __restrict__ counts) {
  int stride = gridDim.x * blockDim.x;
  for (int i = blockIdx.x * blockDim.x + threadIdx.x; i < NPTS; i += stride)
    atomicAdd(&counts[idx[i]], 1);
}

__global__ void k_scan(const int* __restrict__ counts, int* __restrict__ offsets) {
  __shared__ int part[1024];
  __shared__ int sums[32];
  int t = threadIdx.x;
  int loc[32];
  int s = 0;
#pragma unroll
  for (int j = 0; j < 32; ++j) { loc[j] = counts[t * 32 + j]; s += loc[j]; }
  part[t] = s;
  __syncthreads();
  if (t < 32) {
    int run = 0;
    for (int j = 0; j < 32; ++j) { int tmp = part[t * 32 + j]; part[t * 32 + j] = run; run += tmp; }
    sums[t] = run;
  }
  __syncthreads();
  if (t == 0) {
    int run = 0;
    for (int i = 0; i < 32; ++i) { int tmp = sums[i]; sums[i] = run; run += tmp; }
  }
  __syncthreads();
  int b = part[t] + sums[t >> 5];
#pragma unroll
  for (int j = 0; j < 32; ++j) { offsets[t * 32 + j] = b; b += loc[j]; }
  if (t == 1023) offsets[NVOX] = b;
}

__global__ void k_scat(const int* __restrict__ idx, const int* __restrict__ offsets,
                       int* __restrict__ cursor, int* __restrict__ sp, int* __restrict__ sv) {
  int stride = gridDim.x * blockDim.x;
  for (int i = blockIdx.x * blockDim.x + threadIdx.x; i < NPTS; i += stride) {
    int v = idx[i];
    int pos = offsets[v] + atomicAdd(&cursor[v], 1);
    sp[pos] = i;
    sv[pos] = v;
  }
}

// ---------- weight transpose+cast: Wt[n][k] = (f16)W[k][n] ----------
__global__ void k_wcast(const float* __restrict__ W, f16* __restrict__ Wt, int K, int N) {
  int g = blockIdx.x * blockDim.x + threadIdx.x;
  if (g >= K * N) return;
  int k = g / N, n = g % N;
  Wt[n * K + k] = (f16)W[g];
}

__global__ void k_castf(const float* __restrict__ in, f16* __restrict__ out, int n) {
  int stride = gridDim.x * blockDim.x;
  for (int i = blockIdx.x * blockDim.x + threadIdx.x; i < n; i += stride)
    out[i] = (f16)in[i];
}

// ---------- generic f16 MFMA GEMM (validated round-4 core) -----------------
// 256 thr, 4 waves 2x2, 128x128 tile; N=256 via NT column-half blocks.
// MODEA 0: A'[r]=A[tm*128+r]; MODEA 2: mlp1 on the fly (K=64).
// SCATTER: run-reduced sorted scatter-max; WRITEO: dense output.
template <int K, int N, int MODEA, bool SCATTER, bool OUTF32, bool WRITEO>
__global__ __launch_bounds__(256, 3) void k_gemm(
    const f16* __restrict__ A,
    const int* __restrict__ sv, const int* __restrict__ sp,
    const int* __restrict__ offs,
    const float* __restrict__ x, const float* __restrict__ W1, const float* __restrict__ b1,
    const f16* __restrict__ Bt,   // [N][K] pre-transposed
    const float* __restrict__ bias,
    f16* __restrict__ Of16, float* __restrict__ Of32, int row0) {
  constexpr int NT = N / 128;
  __shared__ __align__(16) char smem[32768];
  __shared__ float xs[MODEA == 2 ? 768 : 1];
  __shared__ int svp[MODEA == 2 ? 128 : 1];
  __shared__ int svx[SCATTER ? 128 : 1];
  f16* As = (f16*)smem;            // [128][64] per K-tile, 16B chunks XOR-swizzled
  f16* Bs = As + 128 * 64;

  int nwg = gridDim.x;             // all grids are multiples of 8
  int bid = blockIdx.x;
  int q = nwg >> 3;
  int swz = (bid & 7) * q + (bid >> 3);   // bijective XCD swizzle
  int tm = swz / NT, tn = swz % NT;
  int t = threadIdx.x;

  if (MODEA == 2) { if (t < 128) svp[t] = sp[row0 + tm * 128 + t]; }
  if (SCATTER) { if (t < 128) svx[t] = sv[row0 + tm * 128 + t]; }
  if (MODEA == 2) __syncthreads();

  int l = t & 63, w = t >> 6;
  int wm = w >> 1, wn = w & 1;
  int lrow = l & 15, lk = l >> 4;
  f32x4 acc[4][4] = {};

  constexpr int KT = K / 64;
#pragma unroll
  for (int kt = 0; kt < KT; ++kt) {
    int k0 = kt * 64;
#pragma unroll
    for (int i = 0; i < 4; ++i) {
      int n = i * 32 + (t >> 3);
      int clog = (t & 7) ^ (n & 7);
      GLDS16(Bt + (size_t)(tn * 128 + n) * K + k0 + clog * 8, Bs + i * 2048 + t * 8);
    }
    if constexpr (MODEA == 2) {
      for (int g = t; g < 768; g += 256) xs[g] = x[(size_t)svp[g / 6] * 6 + (g % 6)];
      __syncthreads();
      int j = t & 63;
      float wv[6];
#pragma unroll
      for (int i = 0; i < 6; ++i) wv[i] = W1[i * 64 + j];
      float bb = b1[j];
      int rb = (t >> 6) * 32;
#pragma unroll
      for (int rr = 0; rr < 32; ++rr) {
        int row = rb + rr;
        float a = bb;
#pragma unroll
        for (int i = 0; i < 6; ++i) a += xs[row * 6 + i] * wv[i];
        As[row * 64 + (((j >> 3) ^ (row & 7)) << 3) + (j & 7)] = (f16)fmaxf(a, 0.f);
      }
    } else {
#pragma unroll
      for (int i = 0; i < 4; ++i) {
        int row = i * 32 + (t >> 3);
        int clog = (t & 7) ^ (row & 7);
        GLDS16(A + (size_t)(tm * 128 + row) * K + k0 + clog * 8, As + i * 2048 + t * 8);
      }
    }
    __syncthreads();
#pragma unroll
    for (int ks = 0; ks < 2; ++ks) {
      f16x8 af[4], bf[4];
#pragma unroll
      for (int m = 0; m < 4; ++m) {
        int row = wm * 64 + m * 16 + lrow;
        int cp = (ks * 4 + lk) ^ (row & 7);
        af[m] = *(const f16x8*)(As + row * 64 + cp * 8);
      }
#pragma unroll
      for (int n = 0; n < 4; ++n) {
        int col = wn * 64 + n * 16 + lrow;
        int cp = (ks * 4 + lk) ^ (col & 7);
        bf[n] = *(const f16x8*)(Bs + col * 64 + cp * 8);
      }
#pragma unroll
      for (int m = 0; m < 4; ++m)
#pragma unroll
        for (int n = 0; n < 4; ++n)
          acc[m][n] = __builtin_amdgcn_mfma_f32_16x16x32_f16(af[m], bf[n], acc[m][n], 0, 0, 0);
    }
    __syncthreads();
  }

  if constexpr (WRITEO) {
#pragma unroll
    for (int m = 0; m < 4; ++m)
#pragma unroll
      for (int n = 0; n < 4; ++n)
#pragma unroll
        for (int j = 0; j < 4; ++j) {
          int row = wm * 64 + m * 16 + lk * 4 + j;       // C/D: row=(l>>4)*4+j
          int gc  = tn * 128 + wn * 64 + n * 16 + lrow;  // col=l&15
          float val = fmaxf(acc[m][n][j] + bias[gc], 0.f);
          if constexpr (OUTF32) Of32[(size_t)(tm * 128 + row) * N + gc] = val;
          else                  Of16[(size_t)(tm * 128 + row) * N + gc] = (f16)val;
        }
  }

  if constexpr (SCATTER) {
    f16* tile = (f16*)smem;   // [128][128] f16 (32KB, reuses As/Bs)
#pragma unroll
    for (int m = 0; m < 4; ++m)
#pragma unroll
      for (int n = 0; n < 4; ++n)
#pragma unroll
        for (int j = 0; j < 4; ++j) {
          int row = wm * 64 + m * 16 + lk * 4 + j;
          int col = wn * 64 + n * 16 + lrow;
          tile[row * 128 + col] =
              (f16)fmaxf(acc[m][n][j] + bias[tn * 128 + col], 0.f);
        }
    __syncthreads();
    int c = t & 127, h = t >> 7;    // 2 segments x 64 rows
    int r0l = h * 64;
    int gc = tn * 128 + c;
    int grow0 = row0 + tm * 128 + r0l;
    float run = 0.f;
    int curv = svx[r0l];
    for (int r = r0l; r < r0l + 64; ++r) {
      int v = svx[r];
      if (v != curv) {
        bool inter = (offs[curv] >= grow0) && (offs[curv + 1] <= grow0 + 64);
        if (inter) Of32[(size_t)curv * N + gc] = run;
        else atomicMax((int*)&Of32[(size_t)curv * N + gc], __float_as_int(run));
        curv = v; run = 0.f;
      }
      run = fmaxf(run, (float)tile[r * 128 + c]);
    }
    bool inter = (offs[curv] >= grow0) && (offs[curv + 1] <= grow0 + 64);
    if (inter) Of32[(size_t)curv * N + gc] = run;
    else atomicMax((int*)&Of32[(size_t)curv * N + gc], __float_as_int(run));
  }
}

// ---------- fused stage 2 v2: mm3 + mm4 + scatter-max, pf4 in LDS ----------
// 64 rows/block, 512 thr / 8 waves: wave w handles cols [w*32, w*32+32) of
// the full 256-wide output (both halves concurrently -> half the phases).
// pf4/pf5: [64][264] padded (row stride 528B) -> uniform bank spread for
// b128 reads (8/bank, optimal) and 4-way (vs 8-way) on f16 writes.
__global__ __launch_bounds__(512, 2) void k_stage2(
    const f16* __restrict__ pf2, const f16* __restrict__ occ1,
    const int* __restrict__ sv, const int* __restrict__ offs,
    const f16* __restrict__ W3t, const float* __restrict__ b3,
    const f16* __restrict__ W4t, const float* __restrict__ b4,
    float* __restrict__ vox2f, int row0) {
  // As 8192B | BsRegion 33792B (Bs[256][64] 32KB / pf5[64][264]) | pf4 33792B
  __shared__ __align__(16) char smem[8192 + 33792 + 33792];
  __shared__ int svx[64];
  f16* As  = (f16*)smem;              // [64][64], 16B-chunk XOR-swizzled
  f16* Bs  = (f16*)(smem + 8192);     // [256][64], 16B-chunk XOR-swizzled
  f16* pf5 = Bs;                      // [64][264] f16, overlays Bs after mm4
  f16* pf4 = (f16*)(smem + 8192 + 33792);   // [64][264], linear padded

  int nwg = gridDim.x;
  int bid = blockIdx.x;
  int q = nwg >> 3;
  int bm = (bid & 7) * q + (bid >> 3);   // bijective XCD swizzle
  int t = threadIdx.x;
  if (t < 64) svx[t] = sv[row0 + bm * 64 + t];
  __syncthreads();

  int l = t & 63, w = t >> 6;
  int lrow = l & 15, lk = l >> 4;

  // ---------------- mm3: pf4 = relu(concat(occ1[sv], pf2) @ W3 + b3) -------
  {
    f32x4 acc[4][2] = {};
#pragma unroll
    for (int kt = 0; kt < 4; ++kt) {
      int k0 = kt * 64;
#pragma unroll
      for (int i = 0; i < 4; ++i) {          // stage B: W3t[n 0..255][k0..]
        int g = i * 512 + t;
        int n = g >> 3;
        int clog = (g & 7) ^ (n & 7);
        GLDS16(W3t + (size_t)n * 256 + k0 + clog * 8, Bs + g * 8);
      }
      {                                      // stage A: gather-concat, 1 issue
        int r = t >> 3;
        int clog = (t & 7) ^ (r & 7);
        const f16* src;
        if (k0 < 128) src = occ1 + (size_t)svx[r] * 128 + k0 + clog * 8;
        else          src = pf2 + (size_t)(bm * 64 + r) * 128 + (k0 - 128) + clog * 8;
        GLDS16(src, As + t * 8);
      }
      __syncthreads();
#pragma unroll
      for (int ks = 0; ks < 2; ++ks) {
        f16x8 af[4], bf[2];
#pragma unroll
        for (int m = 0; m < 4; ++m) {
          int row = m * 16 + lrow;
          int cp = (ks * 4 + lk) ^ (row & 7);
          af[m] = *(const f16x8*)(As + row * 64 + cp * 8);
        }
#pragma unroll
        for (int n = 0; n < 2; ++n) {
          int col = w * 32 + n * 16 + lrow;
          int cp = (ks * 4 + lk) ^ (col & 7);
          bf[n] = *(const f16x8*)(Bs + col * 64 + cp * 8);
        }
#pragma unroll
        for (int m = 0; m < 4; ++m)
#pragma unroll
          for (int n = 0; n < 2; ++n)
            acc[m][n] = __builtin_amdgcn_mfma_f32_16x16x32_f16(af[m], bf[n], acc[m][n], 0, 0, 0);
      }
      __syncthreads();
    }
    // pf4 write: relu+bias, padded-linear layout
#pragma unroll
    for (int m = 0; m < 4; ++m)
#pragma unroll
      for (int n = 0; n < 2; ++n)
#pragma unroll
        for (int j = 0; j < 4; ++j) {
          int row  = m * 16 + lk * 4 + j;      // C/D: row=(l>>4)*4+j, col=l&15
          int colg = w * 32 + n * 16 + lrow;
          pf4[row * 264 + colg] = (f16)fmaxf(acc[m][n][j] + b3[colg], 0.f);
        }
  }
  __syncthreads();   // pf4 complete; Bs reads done -> safe to restage

  // ---------------- mm4 + scatter: vox2f = segmax(relu(pf4 @ W4 + b4)) -----
  {
    f32x4 acc[4][2] = {};
#pragma unroll
    for (int kt = 0; kt < 4; ++kt) {
      int k0 = kt * 64;
#pragma unroll
      for (int i = 0; i < 4; ++i) {          // stage B: W4t[n 0..255][k0..]
        int g = i * 512 + t;
        int n = g >> 3;
        int clog = (g & 7) ^ (n & 7);
        GLDS16(W4t + (size_t)n * 256 + k0 + clog * 8, Bs + g * 8);
      }
      __syncthreads();
#pragma unroll
      for (int ks = 0; ks < 2; ++ks) {
        f16x8 af[4], bf[2];
#pragma unroll
        for (int m = 0; m < 4; ++m) {        // A from padded-linear pf4
          int row = m * 16 + lrow;
          int chunk = kt * 8 + ks * 4 + lk;  // absolute K-chunk 0..31
          af[m] = *(const f16x8*)(pf4 + row * 264 + chunk * 8);
        }
#pragma unroll
        for (int n = 0; n < 2; ++n) {
          int col = w * 32 + n * 16 + lrow;
          int cp = (ks * 4 + lk) ^ (col & 7);
          bf[n] = *(const f16x8*)(Bs + col * 64 + cp * 8);
        }
#pragma unroll
        for (int m = 0; m < 4; ++m)
#pragma unroll
          for (int n = 0; n < 2; ++n)
            acc[m][n] = __builtin_amdgcn_mfma_f32_16x16x32_f16(af[m], bf[n], acc[m][n], 0, 0, 0);
      }
      __syncthreads();
    }
    // pf5 -> BsRegion (Bs dead after last barrier)
#pragma unroll
    for (int m = 0; m < 4; ++m)
#pragma unroll
      for (int n = 0; n < 2; ++n)
#pragma unroll
        for (int j = 0; j < 4; ++j) {
          int row  = m * 16 + lk * 4 + j;
          int colg = w * 32 + n * 16 + lrow;
          pf5[row * 264 + colg] = (f16)fmaxf(acc[m][n][j] + b4[colg], 0.f);
        }
    __syncthreads();
    // scan: 256 cols x 2 row-segments of 32; interior plain store, edge atomic
    int c = t & 255, seg = t >> 8;
    int r0l = seg * 32;
    int grow0 = row0 + bm * 64 + r0l;
    float run = 0.f;
    int curv = svx[r0l];
    for (int r = r0l; r < r0l + 32; ++r) {
      int v = svx[r];
      if (v != curv) {
        bool inter = (offs[curv] >= grow0) && (offs[curv + 1] <= grow0 + 32);
        if (inter) vox2f[(size_t)curv * 256 + c] = run;
        else atomicMax((int*)&vox2f[(size_t)curv * 256 + c], __float_as_int(run));
        curv = v; run = 0.f;
      }
      run = fmaxf(run, (float)pf5[r * 264 + c]);
    }
    bool inter = (offs[curv] >= grow0) && (offs[curv + 1] <= grow0 + 32);
    if (inter) vox2f[(size_t)curv * 256 + c] = run;
    else atomicMax((int*)&vox2f[(size_t)curv * 256 + c], __float_as_int(run));
  }
}

extern "C" void kernel_launch(void* const* d_in, const int* in_sizes, int n_in,
                              void* d_out, int out_size, void* d_ws, size_t ws_size,
                              hipStream_t stream) {
  const float* x   = (const float*)d_in[0];
  const int*  idxr = (const int*)d_in[1];
  const float* W1  = (const float*)d_in[3];
  const float* b1  = (const float*)d_in[4];
  const float* W2  = (const float*)d_in[5];
  const float* b2  = (const float*)d_in[6];
  const float* Wv1 = (const float*)d_in[7];
  const float* bv1 = (const float*)d_in[8];
  const float* W3  = (const float*)d_in[9];
  const float* b3  = (const float*)d_in[10];
  const float* W4  = (const float*)d_in[11];
  const float* b4  = (const float*)d_in[12];
  const float* Wv2 = (const float*)d_in[13];
  const float* bv2 = (const float*)d_in[14];
  float* out = (float*)d_out;

  char* ws = (char*)d_ws;
  size_t off = 0;
  auto alloc = [&](size_t bytes) {
    void* p = ws + off;
    off = (off + bytes + 255) & ~(size_t)255;
    return p;
  };
  int* idx     = (int*)alloc((size_t)NPTS * 4);
  int* counts  = (int*)alloc((size_t)NVOX * 4);
  int* cursor  = (int*)alloc((size_t)NVOX * 4);
  int* offs    = (int*)alloc((size_t)(NVOX + 1) * 4);
  int* sp      = (int*)alloc((size_t)NPTS * 4);
  int* sv      = (int*)alloc((size_t)NPTS * 4);
  f16* W2t     = (f16*)alloc(64 * 128 * 2);
  f16* Wv1t    = (f16*)alloc(128 * 128 * 2);
  f16* W3t     = (f16*)alloc(256 * 256 * 2);
  f16* W4t     = (f16*)alloc(256 * 256 * 2);
  f16* Wv2t    = (f16*)alloc(256 * 256 * 2);
  float* vox1f = (float*)alloc((size_t)NVOX * 128 * 4);
  f16* vox1h   = (f16*)alloc((size_t)NVOX * 128 * 2);
  f16* occ1    = (f16*)alloc((size_t)NVOX * 128 * 2);
  float* vox2f = (float*)alloc((size_t)NVOX * 256 * 4);

  // adaptive: materialize pf2 fully if workspace allows, else chunked recompute
  size_t rem = (ws_size > off) ? ws_size - off : 0;
  bool PF2FULL = rem >= (size_t)NPTS * 256 + 4096;
  int CH = 65536;
  f16* pf2   = (f16*)alloc(PF2FULL ? (size_t)NPTS * 256 : (size_t)CH * 256);
  f16* vox2h = pf2;   // overlay: pf2/pf2c dead once stage2 done (16MB fits both)

  hipMemsetAsync(counts, 0, (size_t)NVOX * 4, stream);
  hipMemsetAsync(cursor, 0, (size_t)NVOX * 4, stream);
  hipMemsetAsync(vox1f, 0, (size_t)NVOX * 128 * 4, stream);
  hipMemsetAsync(vox2f, 0, (size_t)NVOX * 256 * 4, stream);

  k_fixidx<<<2048, 256, 0, stream>>>(idxr, idx);
  k_wcast<<<(64 * 128 + 255) / 256, 256, 0, stream>>>(W2, W2t, 64, 128);
  k_wcast<<<(128 * 128 + 255) / 256, 256, 0, stream>>>(Wv1, Wv1t, 128, 128);
  k_wcast<<<(256 * 256 + 255) / 256, 256, 0, stream>>>(W3, W3t, 256, 256);
  k_wcast<<<(256 * 256 + 255) / 256, 256, 0, stream>>>(W4, W4t, 256, 256);
  k_wcast<<<(256 * 256 + 255) / 256, 256, 0, stream>>>(Wv2, Wv2t, 256, 256);
  k_hist<<<2048, 256, 0, stream>>>(idx, counts);
  k_scan<<<1, 1024, 0, stream>>>(counts, offs);
  k_scat<<<2048, 256, 0, stream>>>(idx, offs, cursor, sp, sv);

  // P1: fused mlp1+mm2 + segment-max -> vox1f (also writes pf2 when it fits)
  if (PF2FULL)
    k_gemm<64, 128, 2, true, false, true><<<NPTS / 128, 256, 0, stream>>>(
        nullptr, sv, sp, offs, x, W1, b1, W2t, b2, pf2, vox1f, 0);
  else
    k_gemm<64, 128, 2, true, false, false><<<NPTS / 128, 256, 0, stream>>>(
        nullptr, sv, sp, offs, x, W1, b1, W2t, b2, nullptr, vox1f, 0);
  k_castf<<<2048, 256, 0, stream>>>(vox1f, vox1h, NVOX * 128);
  // mmv1: occ1 = relu(vox1 @ Wv1 + bv1)
  k_gemm<128, 128, 0, false, false, true><<<NVOX / 128, 256, 0, stream>>>(
      vox1h, nullptr, nullptr, nullptr, nullptr, nullptr, nullptr,
      Wv1t, bv1, occ1, nullptr, 0);

  // stage 2: fused mm3+mm4+scatter (pf4 in LDS)
  if (PF2FULL) {
    k_stage2<<<NPTS / 64, 512, 0, stream>>>(
        pf2, occ1, sv, offs, W3t, b3, W4t, b4, vox2f, 0);
  } else {
    for (int c = 0; c < NPTS / CH; ++c) {
      int row0 = c * CH;
      k_gemm<64, 128, 2, false, false, true><<<CH / 128, 256, 0, stream>>>(
          nullptr, nullptr, sp, nullptr, x, W1, b1, W2t, b2, pf2, nullptr, row0);
      k_stage2<<<CH / 64, 512, 0, stream>>>(
          pf2, occ1, sv, offs, W3t, b3, W4t, b4, vox2f, row0);
    }
  }

  k_castf<<<2048, 256, 0, stream>>>(vox2f, vox2h, NVOX * 256);
  // mmv2: out = relu(vox2 @ Wv2 + bv2), f32 output via MFMA
  k_gemm<256, 256, 0, false, true, true><<<(NVOX / 128) * 2, 256, 0, stream>>>(
      vox2h, nullptr, nullptr, nullptr, nullptr, nullptr, nullptr,
      Wv2t, bv2, nullptr, out, 0);
}